// Round 2
// baseline (140.418 us; speedup 1.0000x reference)
//
#include <hip/hip_runtime.h>
#include <math.h>

#define B_   32
#define N_   8192
#define H_   128
#define G_   10
#define TOKS (B_*N_)
#define THREADS 512
#define WAVES 8
#define TPW 32
#define TPB 256
#define LDW 136   // padded LDS row stride in bf16 elems (272B: breaks bank conflicts, 16B aligned)

typedef short bf16x8 __attribute__((ext_vector_type(8)));
typedef float f32x4 __attribute__((ext_vector_type(4)));

__device__ __forceinline__ short f2bf(float f) {
  union { float f; unsigned u; } v; v.f = f;
  unsigned r = v.u + 0x7fffu + ((v.u >> 16) & 1u);  // RNE
  return (short)(r >> 16);
}

__device__ __forceinline__ float rmax16(float v) {
  v = fmaxf(v, __shfl_xor(v, 1, 16));
  v = fmaxf(v, __shfl_xor(v, 2, 16));
  v = fmaxf(v, __shfl_xor(v, 4, 16));
  v = fmaxf(v, __shfl_xor(v, 8, 16));
  return v;
}
__device__ __forceinline__ float rsum16(float v) {
  v += __shfl_xor(v, 1, 16);
  v += __shfl_xor(v, 2, 16);
  v += __shfl_xor(v, 4, 16);
  v += __shfl_xor(v, 8, 16);
  return v;
}

__global__ __launch_bounds__(64) void init_kernel(float* out, float* ws) {
  int t = threadIdx.x;
  if (t < 33) out[t] = 0.0f;   // score[32] + loss[1]
  if (t < 2)  ws[t]  = 0.0f;   // loss_sum, mask_count
}

__global__ __launch_bounds__(64) void fin_kernel(float* out, const float* ws) {
  if (threadIdx.x == 0) out[32] = ws[0] / fmaxf(ws[1], 1.0f);
}

__global__ __launch_bounds__(THREADS, 1)
void rtm_main(const float* __restrict__ feat,
              const float* __restrict__ dist,
              const int* __restrict__ dmask,   // bool input -> pushed as int32 per harness contract
              const float* __restrict__ w1_0, const float* __restrict__ b1_0,
              const float* __restrict__ w2_0, const float* __restrict__ b2_0,
              const float* __restrict__ w1_1, const float* __restrict__ b1_1,
              const float* __restrict__ w2_1, const float* __restrict__ b2_1,
              const float* __restrict__ w1_2, const float* __restrict__ b1_2,
              const float* __restrict__ w2_2, const float* __restrict__ b2_2,
              float* __restrict__ out, float* __restrict__ ws) {
  // LDS: W1^T bf16 [head][hidden][input], W2^T bf16 [head][g(pad16)][input],
  // biases f32, per-wave hidden staging, reduction scratch.  ~150.5 KiB total.
  __shared__ __align__(16) short w1s[3][H_][LDW];
  __shared__ __align__(16) short w2s[3][16][LDW];
  __shared__ float b1s[3][H_];
  __shared__ float b2s[3][16];
  __shared__ __align__(16) short hids[WAVES][16][LDW];
  __shared__ float red[WAVES][3];

  const int tid = threadIdx.x;
  const float* w1p[3] = {w1_0, w1_1, w1_2};
  const float* w2p[3] = {w2_0, w2_1, w2_2};
  const float* b1p[3] = {b1_0, b1_1, b1_2};
  const float* b2p[3] = {b2_0, b2_1, b2_2};

  // ---- stage weights to LDS (once per block) ----
  for (int h = 0; h < 3; ++h) {
    for (int idx = tid; idx < H_*H_; idx += THREADS) {
      int i = idx >> 7, j = idx & 127;           // w1[i][j], i=input, j=hidden
      w1s[h][j][i] = f2bf(w1p[h][idx]);          // transposed
    }
    for (int idx = tid; idx < 16*H_; idx += THREADS) {
      int g = idx >> 7, k = idx & 127;
      w2s[h][g][k] = (g < G_) ? f2bf(w2p[h][(size_t)k*G_ + g]) : (short)0;
    }
    if (tid < H_) b1s[h][tid] = b1p[h][tid];
    if (tid < 16) b2s[h][tid] = (tid < G_) ? b2p[h][tid] : 0.0f;
  }
  __syncthreads();

  const int wave = tid >> 6;
  const int lane = tid & 63;
  const int q  = lane >> 4;   // quad index 0..3
  const int lg = lane & 15;   // lane-in-group
  const long wtok0 = (long)blockIdx.x * TPB + (long)wave * TPW;

  // ---- load A fragments (features, f32 -> bf16) for 2 M-tiles x 4 K-chunks ----
  // A-frag layout (16x16x32): lane holds A[row=lane&15][k=(lane>>4)*8 + j]
  bf16x8 a1[2][4];
#pragma unroll
  for (int mt = 0; mt < 2; ++mt) {
    const float* fr = feat + (wtok0 + mt*16 + lg) * (long)H_;
#pragma unroll
    for (int c = 0; c < 4; ++c) {
      const float4* p = reinterpret_cast<const float4*>(fr + c*32 + q*8);
      float4 lo = p[0], hi = p[1];
      bf16x8 a;
      a[0]=f2bf(lo.x); a[1]=f2bf(lo.y); a[2]=f2bf(lo.z); a[3]=f2bf(lo.w);
      a[4]=f2bf(hi.x); a[5]=f2bf(hi.y); a[6]=f2bf(hi.z); a[7]=f2bf(hi.w);
      a1[mt][c] = a;
    }
  }

  // ---- 3 heads x 2 M-tiles: layer1 MFMA -> relu -> LDS -> layer2 MFMA ----
  f32x4 lgt[3][2];
#pragma unroll
  for (int h = 0; h < 3; ++h) {
#pragma unroll
    for (int mt = 0; mt < 2; ++mt) {
      f32x4 acc[8];
#pragma unroll
      for (int nt = 0; nt < 8; ++nt) acc[nt] = (f32x4){0.f,0.f,0.f,0.f};
#pragma unroll
      for (int c = 0; c < 4; ++c) {
#pragma unroll
        for (int nt = 0; nt < 8; ++nt) {
          // B-frag: lane holds B[k=(lane>>4)*8+j][col=lane&15] -> W1^T[col][k]
          bf16x8 bfr = *reinterpret_cast<const bf16x8*>(&w1s[h][nt*16 + lg][c*32 + q*8]);
          acc[nt] = __builtin_amdgcn_mfma_f32_16x16x32_bf16(a1[mt][c], bfr, acc[nt], 0, 0, 0);
        }
      }
      // D layout: row=(lane>>4)*4+r (token), col=lane&15 (hidden) per nt-tile
#pragma unroll
      for (int nt = 0; nt < 8; ++nt) {
#pragma unroll
        for (int r = 0; r < 4; ++r) {
          float v = acc[nt][r] + b1s[h][nt*16 + lg];
          hids[wave][q*4 + r][nt*16 + lg] = f2bf(fmaxf(v, 0.0f));
        }
      }
      __syncthreads();
      f32x4 lacc = (f32x4){0.f,0.f,0.f,0.f};
#pragma unroll
      for (int c = 0; c < 4; ++c) {
        bf16x8 afr = *reinterpret_cast<const bf16x8*>(&hids[wave][lg][c*32 + q*8]);
        bf16x8 bfr = *reinterpret_cast<const bf16x8*>(&w2s[h][lg][c*32 + q*8]);
        lacc = __builtin_amdgcn_mfma_f32_16x16x32_bf16(afr, bfr, lacc, 0, 0, 0);
      }
      float bb = b2s[h][lg];
#pragma unroll
      for (int r = 0; r < 4; ++r) lacc[r] += bb;
      lgt[h][mt] = lacc;
      __syncthreads();
    }
  }

  // ---- epilogue: per token (16-lane group owns 4 tokens; lane's g = lg) ----
  float* out_score = out;
  float* out_pi = out + 33;
  float* out_mu = out + 33 + (size_t)TOKS*G_;
  float* out_sg = out + 33 + 2*(size_t)TOKS*G_;
  const float HLOG2PI = 0.91893853320467274f;   // 0.5*log(2*pi)

  float accP = 0.f, accL = 0.f, accC = 0.f;
#pragma unroll
  for (int mt = 0; mt < 2; ++mt) {
#pragma unroll
    for (int r = 0; r < 4; ++r) {
      long tok = wtok0 + mt*16 + q*4 + r;
      float d = dist[tok];
      bool mk = (dmask[tok] != 0) && (d <= 8.0f);
      bool gv = (lg < G_);

      float lpi = lgt[0][mt][r];
      float lsg = lgt[1][mt][r];
      float lmu = lgt[2][mt][r];

      // softmax(pi) over g
      float m = rmax16(gv ? lpi : -INFINITY);
      float e = gv ? __expf(lpi - m) : 0.f;
      float s = rsum16(e);
      float pi = e / s;

      // sigma = elu(x)+1.4 ; mu = elu(x)+1.0
      float sg = (lsg > 0.f) ? (lsg + 1.4f) : (__expf(lsg) + 0.4f);
      float mu = (lmu > 0.f) ? (lmu + 1.0f) : __expf(lmu);

      float z = (d - mu) / sg;
      float ll = -0.5f*z*z - __logf(sg) - HLOG2PI;

      if (gv) {
        size_t o = (size_t)tok*G_ + lg;
        out_pi[o] = pi; out_mu[o] = mu; out_sg[o] = sg;
      }

      // candidate_loss = -logsumexp(log(pi+eps) + ll)
      float a = gv ? (__logf(pi + 1e-10f) + ll) : -INFINITY;
      float m2 = rmax16(a);
      float e2 = gv ? __expf(a - m2) : 0.f;
      float s2 = rsum16(e2);
      float closs = -(m2 + __logf(s2));

      // prob = sum(exp(ll)*pi) / (d*d + eps)
      float pn = gv ? (__expf(ll) * pi) : 0.f;
      float s3 = rsum16(pn);
      float prob = s3 / (d*d + 1e-10f);

      if (lg == 0 && mk) { accP += prob; accL += closs; accC += 1.f; }
    }
  }

  // wave-level reduce (group leaders hold partials, others 0)
  accP += __shfl_xor(accP, 16, 64); accP += __shfl_xor(accP, 32, 64);
  accL += __shfl_xor(accL, 16, 64); accL += __shfl_xor(accL, 32, 64);
  accC += __shfl_xor(accC, 16, 64); accC += __shfl_xor(accC, 32, 64);
  if (lane == 0) { red[wave][0] = accP; red[wave][1] = accL; red[wave][2] = accC; }
  __syncthreads();
  if (tid == 0) {
    float sP = 0.f, sL = 0.f, sC = 0.f;
    for (int w = 0; w < WAVES; ++w) { sP += red[w][0]; sL += red[w][1]; sC += red[w][2]; }
    int b = (int)(((long)blockIdx.x * TPB) >> 13);   // all 256 tokens in a block share b
    atomicAdd(&out_score[b], sP);
    atomicAdd(&ws[0], sL);
    atomicAdd(&ws[1], sC);
  }
}

extern "C" void kernel_launch(void* const* d_in, const int* in_sizes, int n_in,
                              void* d_out, int out_size, void* d_ws, size_t ws_size,
                              hipStream_t stream) {
  const float* feat = (const float*)d_in[0];
  const float* dist = (const float*)d_in[1];
  const int* dmask = (const int*)d_in[2];
  float* out = (float*)d_out;
  float* ws  = (float*)d_ws;

  hipLaunchKernelGGL(init_kernel, dim3(1), dim3(64), 0, stream, out, ws);
  hipLaunchKernelGGL(rtm_main, dim3(TOKS/TPB), dim3(THREADS), 0, stream,
      feat, dist, dmask,
      (const float*)d_in[3],  (const float*)d_in[4],  (const float*)d_in[5],  (const float*)d_in[6],
      (const float*)d_in[7],  (const float*)d_in[8],  (const float*)d_in[9],  (const float*)d_in[10],
      (const float*)d_in[11], (const float*)d_in[12], (const float*)d_in[13], (const float*)d_in[14],
      out, ws);
  hipLaunchKernelGGL(fin_kernel, dim3(1), dim3(64), 0, stream, out, ws);
}

// Round 3
// 132.738 us; speedup vs baseline: 1.0579x; 1.0579x over previous
//
#include <hip/hip_runtime.h>
#include <math.h>

#define B_   32
#define N_   8192
#define H_   128
#define G_   10
#define TOKS (B_*N_)
#define THREADS 512
#define WAVES 8
#define TPW 32
#define TPB 256
#define LDW 136   // padded LDS row stride in bf16 elems (272B, 16B-aligned rows)

typedef short bf16x8 __attribute__((ext_vector_type(8)));
typedef float f32x4 __attribute__((ext_vector_type(4)));

// ws layout: [0..1] loss_sum/mask_count floats; weight image at byte WS_IMG_OFF
#define WS_IMG_OFF 256
#define IMG_BYTES  119232          // 3*128*136*2 + 3*16*136*2 + 3*128*4 + 3*16*4
#define IMG_CHUNKS (IMG_BYTES/16)  // 7452 (exact)

struct __align__(16) SMem {
  // ---- first 119232 bytes == prep image, copied verbatim ----
  short w1s[3][H_][LDW];   // W1^T bf16: [head][hidden j][input i]
  short w2s[3][16][LDW];   // W2^T bf16: [head][g pad16][hidden k]
  float b1s[3][H_];
  float b2s[3][16];
  // ---- per-block scratch ----
  short hids[WAVES][16][LDW];
  float red[WAVES][3];
};

__device__ __forceinline__ short f2bf(float f) {
  union { float f; unsigned u; } v; v.f = f;
  unsigned r = v.u + 0x7fffu + ((v.u >> 16) & 1u);  // RNE
  return (short)(r >> 16);
}

__device__ __forceinline__ float rmax16(float v) {
  v = fmaxf(v, __shfl_xor(v, 1, 16));
  v = fmaxf(v, __shfl_xor(v, 2, 16));
  v = fmaxf(v, __shfl_xor(v, 4, 16));
  v = fmaxf(v, __shfl_xor(v, 8, 16));
  return v;
}
__device__ __forceinline__ float rsum16(float v) {
  v += __shfl_xor(v, 1, 16);
  v += __shfl_xor(v, 2, 16);
  v += __shfl_xor(v, 4, 16);
  v += __shfl_xor(v, 8, 16);
  return v;
}

__global__ __launch_bounds__(64) void init_kernel(float* out, float* ws) {
  int t = threadIdx.x;
  if (t < 33) out[t] = 0.0f;   // score[32] + loss[1]
  if (t < 2)  ws[t]  = 0.0f;   // loss_sum, mask_count
}

__global__ __launch_bounds__(64) void fin_kernel(float* out, const float* ws) {
  if (threadIdx.x == 0) out[32] = ws[0] / fmaxf(ws[1], 1.0f);
}

// Convert+transpose+pad all weights once into the LDS image in ws.
__global__ __launch_bounds__(256) void prep_kernel(
    const float* __restrict__ w1_0, const float* __restrict__ b1_0,
    const float* __restrict__ w2_0, const float* __restrict__ b2_0,
    const float* __restrict__ w1_1, const float* __restrict__ b1_1,
    const float* __restrict__ w2_1, const float* __restrict__ b2_1,
    const float* __restrict__ w1_2, const float* __restrict__ b1_2,
    const float* __restrict__ w2_2, const float* __restrict__ b2_2,
    short* __restrict__ img) {
  const float* w1p[3] = {w1_0, w1_1, w1_2};
  const float* w2p[3] = {w2_0, w2_1, w2_2};
  const float* b1p[3] = {b1_0, b1_1, b1_2};
  const float* b2p[3] = {b2_0, b2_1, b2_2};
  int t = blockIdx.x * 256 + threadIdx.x;
  int stride = gridDim.x * 256;
  // W1^T region: 3*128*136 shorts
  for (int idx = t; idx < 3*H_*LDW; idx += stride) {
    int h = idx / (H_*LDW), rem = idx - h*(H_*LDW);
    int j = rem / LDW, i = rem - j*LDW;
    img[idx] = (i < H_) ? f2bf(w1p[h][i*H_ + j]) : (short)0;
  }
  // W2^T region: 3*16*136 shorts
  for (int idx = t; idx < 3*16*LDW; idx += stride) {
    int h = idx / (16*LDW), rem = idx - h*(16*LDW);
    int g = rem / LDW, k = rem - g*LDW;
    img[3*H_*LDW + idx] = (g < G_ && k < H_) ? f2bf(w2p[h][k*G_ + g]) : (short)0;
  }
  // bias region (floats) right after the short regions
  float* bimg = (float*)(img + 3*H_*LDW + 3*16*LDW);
  if (t < 3*H_ + 3*16) {
    if (t < 3*H_) { int h = t >> 7, j = t & 127; bimg[t] = b1p[h][j]; }
    else { int i2 = t - 3*H_; int h = i2 >> 4, g = i2 & 15;
           bimg[t] = (g < G_) ? b2p[h][g] : 0.0f; }
  }
}

template<int PREP>
__global__ __launch_bounds__(THREADS, 1)
void rtm_main(const float* __restrict__ feat,
              const float* __restrict__ dist,
              const int* __restrict__ dmask,
              const float* __restrict__ img,      // prep image (PREP=1)
              const float* __restrict__ w1_0, const float* __restrict__ b1_0,
              const float* __restrict__ w2_0, const float* __restrict__ b2_0,
              const float* __restrict__ w1_1, const float* __restrict__ b1_1,
              const float* __restrict__ w2_1, const float* __restrict__ b2_1,
              const float* __restrict__ w1_2, const float* __restrict__ b1_2,
              const float* __restrict__ w2_2, const float* __restrict__ b2_2,
              float* __restrict__ out, float* __restrict__ ws) {
  __shared__ SMem sm;

  const int tid = threadIdx.x;
  const int wave = tid >> 6;
  const int lane = tid & 63;
  const int q  = lane >> 4;
  const int lg = lane & 15;
  const long wtok0 = (long)blockIdx.x * TPB + (long)wave * TPW;

  // ---- issue feature loads FIRST (HBM latency hides under weight staging) ----
  float4 fv[2][4][2];
#pragma unroll
  for (int mt = 0; mt < 2; ++mt) {
    const float* fr = feat + (wtok0 + mt*16 + lg) * (long)H_;
#pragma unroll
    for (int c = 0; c < 4; ++c) {
      const float4* p = reinterpret_cast<const float4*>(fr + c*32 + q*8);
      fv[mt][c][0] = p[0];
      fv[mt][c][1] = p[1];
    }
  }

  // ---- stage weights to LDS ----
  if constexpr (PREP) {
    const f32x4* src = reinterpret_cast<const f32x4*>(img);
    f32x4* dst = reinterpret_cast<f32x4*>(&sm);
    for (int i = tid; i < IMG_CHUNKS; i += THREADS) dst[i] = src[i];
  } else {
    const float* w1p[3] = {w1_0, w1_1, w1_2};
    const float* w2p[3] = {w2_0, w2_1, w2_2};
    const float* b1p[3] = {b1_0, b1_1, b1_2};
    const float* b2p[3] = {b2_0, b2_1, b2_2};
    for (int h = 0; h < 3; ++h) {
      for (int idx = tid; idx < H_*H_; idx += THREADS) {
        int i = idx >> 7, j = idx & 127;
        sm.w1s[h][j][i] = f2bf(w1p[h][idx]);
      }
      for (int idx = tid; idx < 16*H_; idx += THREADS) {
        int g = idx >> 7, k = idx & 127;
        sm.w2s[h][g][k] = (g < G_) ? f2bf(w2p[h][(size_t)k*G_ + g]) : (short)0;
      }
      if (tid < H_) sm.b1s[h][tid] = b1p[h][tid];
      if (tid < 16) sm.b2s[h][tid] = (tid < G_) ? b2p[h][tid] : 0.0f;
    }
  }

  // ---- convert features to bf16 A-fragments while staging is in flight ----
  bf16x8 a1[2][4];
#pragma unroll
  for (int mt = 0; mt < 2; ++mt)
#pragma unroll
    for (int c = 0; c < 4; ++c) {
      float4 lo = fv[mt][c][0], hi = fv[mt][c][1];
      bf16x8 a;
      a[0]=f2bf(lo.x); a[1]=f2bf(lo.y); a[2]=f2bf(lo.z); a[3]=f2bf(lo.w);
      a[4]=f2bf(hi.x); a[5]=f2bf(hi.y); a[6]=f2bf(hi.z); a[7]=f2bf(hi.w);
      a1[mt][c] = a;
    }

  __syncthreads();   // weights visible to all waves (only barrier before reduce)

  // ---- 3 heads x 2 M-tiles; hids is wave-private -> NO barriers in this loop ----
  f32x4 lgt[3][2];
#pragma unroll
  for (int h = 0; h < 3; ++h) {
#pragma unroll
    for (int mt = 0; mt < 2; ++mt) {
      f32x4 acc[8];
#pragma unroll
      for (int nt = 0; nt < 8; ++nt) acc[nt] = (f32x4){0.f,0.f,0.f,0.f};
#pragma unroll
      for (int c = 0; c < 4; ++c) {
#pragma unroll
        for (int nt = 0; nt < 8; ++nt) {
          bf16x8 bfr = *reinterpret_cast<const bf16x8*>(&sm.w1s[h][nt*16 + lg][c*32 + q*8]);
          acc[nt] = __builtin_amdgcn_mfma_f32_16x16x32_bf16(a1[mt][c], bfr, acc[nt], 0, 0, 0);
        }
      }
      // D layout: row=(lane>>4)*4+r (token), col=lane&15 (hidden)
#pragma unroll
      for (int nt = 0; nt < 8; ++nt) {
#pragma unroll
        for (int r = 0; r < 4; ++r) {
          float v = acc[nt][r] + sm.b1s[h][nt*16 + lg];
          sm.hids[wave][q*4 + r][nt*16 + lg] = f2bf(fmaxf(v, 0.0f));
        }
      }
      // same-wave LDS FIFO ordering makes write->read safe without barrier
      f32x4 lacc = (f32x4){0.f,0.f,0.f,0.f};
#pragma unroll
      for (int c = 0; c < 4; ++c) {
        bf16x8 afr = *reinterpret_cast<const bf16x8*>(&sm.hids[wave][lg][c*32 + q*8]);
        bf16x8 bfr = *reinterpret_cast<const bf16x8*>(&sm.w2s[h][lg][c*32 + q*8]);
        lacc = __builtin_amdgcn_mfma_f32_16x16x32_bf16(afr, bfr, lacc, 0, 0, 0);
      }
      float bb = sm.b2s[h][lg];
#pragma unroll
      for (int r = 0; r < 4; ++r) lacc[r] += bb;
      lgt[h][mt] = lacc;
    }
  }

  // ---- epilogue ----
  float* out_score = out;
  float* out_pi = out + 33;
  float* out_mu = out + 33 + (size_t)TOKS*G_;
  float* out_sg = out + 33 + 2*(size_t)TOKS*G_;
  const float HLOG2PI = 0.91893853320467274f;

  float accP = 0.f, accL = 0.f, accC = 0.f;
#pragma unroll
  for (int mt = 0; mt < 2; ++mt) {
#pragma unroll
    for (int r = 0; r < 4; ++r) {
      long tok = wtok0 + mt*16 + q*4 + r;
      float d = dist[tok];
      bool mk = (dmask[tok] != 0) && (d <= 8.0f);
      bool gv = (lg < G_);

      float lpi = lgt[0][mt][r];
      float lsg = lgt[1][mt][r];
      float lmu = lgt[2][mt][r];

      float m = rmax16(gv ? lpi : -INFINITY);
      float e = gv ? __expf(lpi - m) : 0.f;
      float s = rsum16(e);
      float pi = e / s;

      float sg = (lsg > 0.f) ? (lsg + 1.4f) : (__expf(lsg) + 0.4f);
      float mu = (lmu > 0.f) ? (lmu + 1.0f) : __expf(lmu);

      float z = (d - mu) / sg;
      float ll = -0.5f*z*z - __logf(sg) - HLOG2PI;

      if (gv) {
        size_t o = (size_t)tok*G_ + lg;
        out_pi[o] = pi; out_mu[o] = mu; out_sg[o] = sg;
      }

      float a = gv ? (__logf(pi + 1e-10f) + ll) : -INFINITY;
      float m2 = rmax16(a);
      float e2 = gv ? __expf(a - m2) : 0.f;
      float s2 = rsum16(e2);
      float closs = -(m2 + __logf(s2));

      float pn = gv ? (__expf(ll) * pi) : 0.f;
      float s3 = rsum16(pn);
      float prob = s3 / (d*d + 1e-10f);

      if (lg == 0 && mk) { accP += prob; accL += closs; accC += 1.f; }
    }
  }

  accP += __shfl_xor(accP, 16, 64); accP += __shfl_xor(accP, 32, 64);
  accL += __shfl_xor(accL, 16, 64); accL += __shfl_xor(accL, 32, 64);
  accC += __shfl_xor(accC, 16, 64); accC += __shfl_xor(accC, 32, 64);
  if (lane == 0) { sm.red[wave][0] = accP; sm.red[wave][1] = accL; sm.red[wave][2] = accC; }
  __syncthreads();
  if (tid == 0) {
    float sP = 0.f, sL = 0.f, sC = 0.f;
    for (int w = 0; w < WAVES; ++w) { sP += sm.red[w][0]; sL += sm.red[w][1]; sC += sm.red[w][2]; }
    int b = (int)(((long)blockIdx.x * TPB) >> 13);
    atomicAdd(&out_score[b], sP);
    atomicAdd(&ws[0], sL);
    atomicAdd(&ws[1], sC);
  }
}

extern "C" void kernel_launch(void* const* d_in, const int* in_sizes, int n_in,
                              void* d_out, int out_size, void* d_ws, size_t ws_size,
                              hipStream_t stream) {
  const float* feat = (const float*)d_in[0];
  const float* dist = (const float*)d_in[1];
  const int* dmask = (const int*)d_in[2];
  float* out = (float*)d_out;
  float* ws  = (float*)d_ws;

  hipLaunchKernelGGL(init_kernel, dim3(1), dim3(64), 0, stream, out, ws);

  bool prep_ok = (ws_size >= (size_t)(WS_IMG_OFF + IMG_BYTES));
  if (prep_ok) {
    short* img = (short*)((char*)d_ws + WS_IMG_OFF);
    hipLaunchKernelGGL(prep_kernel, dim3(116), dim3(256), 0, stream,
        (const float*)d_in[3],  (const float*)d_in[4],  (const float*)d_in[5],  (const float*)d_in[6],
        (const float*)d_in[7],  (const float*)d_in[8],  (const float*)d_in[9],  (const float*)d_in[10],
        (const float*)d_in[11], (const float*)d_in[12], (const float*)d_in[13], (const float*)d_in[14],
        img);
    hipLaunchKernelGGL((rtm_main<1>), dim3(TOKS/TPB), dim3(THREADS), 0, stream,
        feat, dist, dmask, (const float*)img,
        (const float*)d_in[3],  (const float*)d_in[4],  (const float*)d_in[5],  (const float*)d_in[6],
        (const float*)d_in[7],  (const float*)d_in[8],  (const float*)d_in[9],  (const float*)d_in[10],
        (const float*)d_in[11], (const float*)d_in[12], (const float*)d_in[13], (const float*)d_in[14],
        out, ws);
  } else {
    hipLaunchKernelGGL((rtm_main<0>), dim3(TOKS/TPB), dim3(THREADS), 0, stream,
        feat, dist, dmask, (const float*)nullptr,
        (const float*)d_in[3],  (const float*)d_in[4],  (const float*)d_in[5],  (const float*)d_in[6],
        (const float*)d_in[7],  (const float*)d_in[8],  (const float*)d_in[9],  (const float*)d_in[10],
        (const float*)d_in[11], (const float*)d_in[12], (const float*)d_in[13], (const float*)d_in[14],
        out, ws);
  }

  hipLaunchKernelGGL(fin_kernel, dim3(1), dim3(64), 0, stream, out, ws);
}

// Round 4
// 97.242 us; speedup vs baseline: 1.4440x; 1.3650x over previous
//
#include <hip/hip_runtime.h>
#include <math.h>
#include <stdint.h>

#define B_   32
#define N_   8192
#define H_   128
#define G_   10
#define TOKS (B_*N_)
#define THREADS 512
#define WAVES 8
#define TPW 32
#define TPB 256
#define LDW 136   // padded LDS row stride in bf16 elems (272B, 16B-aligned rows)

typedef short bf16x8 __attribute__((ext_vector_type(8)));
typedef short bf16x4 __attribute__((ext_vector_type(4)));
typedef float f32x4 __attribute__((ext_vector_type(4)));

// ws layout: [0..1] loss_sum/mask_count floats; weight image at byte WS_IMG_OFF
#define WS_IMG_OFF 256
#define IMG_BYTES  119232          // 3*128*136*2 + 3*16*136*2 + 3*128*4 + 3*16*4
#define IMG_CHUNKS (IMG_BYTES/16)  // 7452
#define IMG_INSTS  117             // ceil(119232/1024); last inst overshoots 576B into hids pad (safe)

struct __align__(16) SMem {
  // ---- first 119232 bytes == prep image, copied verbatim ----
  short w1s[3][H_][LDW];   // W1^T bf16: [head][hidden j][input i]
  short w2s[3][16][LDW];   // W2^T bf16: [head][g pad16][hidden k]
  float b1s[3][H_];
  float b2s[3][16];
  // ---- per-block scratch (first 576B may get staging overshoot garbage: only pad cols/rows touched before rewrite) ----
  short hids[WAVES][16][LDW];   // [wave][token][j], written b64, read b128
  float red[WAVES][3];
};

__device__ __forceinline__ short f2bf(float f) {
  union { float f; unsigned u; } v; v.f = f;
  unsigned r = v.u + 0x7fffu + ((v.u >> 16) & 1u);  // RNE
  return (short)(r >> 16);
}

__device__ __forceinline__ void async_copy16(void* lds_uniform, const void* gsrc_perlane) {
  __builtin_amdgcn_global_load_lds(
      (const __attribute__((address_space(1))) unsigned int*)gsrc_perlane,
      (__attribute__((address_space(3))) unsigned int*)lds_uniform,
      16, 0, 0);
}

__global__ __launch_bounds__(64) void init_kernel(float* out, float* ws) {
  int t = threadIdx.x;
  if (t < 33) out[t] = 0.0f;   // score[32] + loss[1]
  if (t < 2)  ws[t]  = 0.0f;   // loss_sum, mask_count
}

__global__ __launch_bounds__(64) void fin_kernel(float* out, const float* ws) {
  if (threadIdx.x == 0) out[32] = ws[0] / fmaxf(ws[1], 1.0f);
}

// Convert+transpose+pad all weights once into the LDS image in ws.
__global__ __launch_bounds__(256) void prep_kernel(
    const float* __restrict__ w1_0, const float* __restrict__ b1_0,
    const float* __restrict__ w2_0, const float* __restrict__ b2_0,
    const float* __restrict__ w1_1, const float* __restrict__ b1_1,
    const float* __restrict__ w2_1, const float* __restrict__ b2_1,
    const float* __restrict__ w1_2, const float* __restrict__ b1_2,
    const float* __restrict__ w2_2, const float* __restrict__ b2_2,
    short* __restrict__ img) {
  const float* w1p[3] = {w1_0, w1_1, w1_2};
  const float* w2p[3] = {w2_0, w2_1, w2_2};
  const float* b1p[3] = {b1_0, b1_1, b1_2};
  const float* b2p[3] = {b2_0, b2_1, b2_2};
  int t = blockIdx.x * 256 + threadIdx.x;
  int stride = gridDim.x * 256;
  for (int idx = t; idx < 3*H_*LDW; idx += stride) {
    int h = idx / (H_*LDW), rem = idx - h*(H_*LDW);
    int j = rem / LDW, i = rem - j*LDW;
    img[idx] = (i < H_) ? f2bf(w1p[h][i*H_ + j]) : (short)0;
  }
  for (int idx = t; idx < 3*16*LDW; idx += stride) {
    int h = idx / (16*LDW), rem = idx - h*(16*LDW);
    int g = rem / LDW, k = rem - g*LDW;
    img[3*H_*LDW + idx] = (g < G_ && k < H_) ? f2bf(w2p[h][k*G_ + g]) : (short)0;
  }
  float* bimg = (float*)(img + 3*H_*LDW + 3*16*LDW);
  if (t < 3*H_ + 3*16) {
    if (t < 3*H_) { int h = t >> 7, j = t & 127; bimg[t] = b1p[h][j]; }
    else { int i2 = t - 3*H_; int h = i2 >> 4, g = i2 & 15;
           bimg[t] = (g < G_) ? b2p[h][g] : 0.0f; }
  }
}

template<int PREP>
__global__ __launch_bounds__(THREADS, 1)
void rtm_main(const float* __restrict__ feat,
              const float* __restrict__ dist,
              const int* __restrict__ dmask,
              const float* __restrict__ img,
              const float* __restrict__ w1_0, const float* __restrict__ b1_0,
              const float* __restrict__ w2_0, const float* __restrict__ b2_0,
              const float* __restrict__ w1_1, const float* __restrict__ b1_1,
              const float* __restrict__ w2_1, const float* __restrict__ b2_1,
              const float* __restrict__ w1_2, const float* __restrict__ b1_2,
              const float* __restrict__ w2_2, const float* __restrict__ b2_2,
              float* __restrict__ out, float* __restrict__ ws) {
  __shared__ SMem sm;

  const int tid  = threadIdx.x;
  const int wave = tid >> 6;
  const int lane = tid & 63;
  const int q  = lane >> 4;   // quarter-wave 0..3
  const int lg = lane & 15;   // lane-in-group = token-in-tile / g-row / j-row
  const long wtok0 = (long)blockIdx.x * TPB + (long)wave * TPW;

  // ---- issue dist/mask + feature loads FIRST ----
  float dpre[2]; int mpre[2];
#pragma unroll
  for (int mt = 0; mt < 2; ++mt) {
    long tok = wtok0 + mt*16 + lg;
    dpre[mt] = dist[tok];
    mpre[mt] = dmask[tok];
  }
  float4 fv[2][4][2];
#pragma unroll
  for (int mt = 0; mt < 2; ++mt) {
    const float* fr = feat + (wtok0 + mt*16 + lg) * (long)H_;
#pragma unroll
    for (int c = 0; c < 4; ++c) {
      const float4* p = reinterpret_cast<const float4*>(fr + c*32 + q*8);
      fv[mt][c][0] = p[0];
      fv[mt][c][1] = p[1];
    }
  }

  // ---- stage weight image to LDS (async, no VGPR round trip) ----
  if constexpr (PREP) {
    char* smb = (char*)&sm;
    const char* gimg = (const char*)img;
    for (int i = wave; i < IMG_INSTS; i += WAVES)
      async_copy16(smb + i*1024, gimg + i*1024 + lane*16);
  } else {
    const float* w1p[3] = {w1_0, w1_1, w1_2};
    const float* w2p[3] = {w2_0, w2_1, w2_2};
    const float* b1p[3] = {b1_0, b1_1, b1_2};
    const float* b2p[3] = {b2_0, b2_1, b2_2};
    for (int h = 0; h < 3; ++h) {
      for (int idx = tid; idx < H_*H_; idx += THREADS) {
        int i = idx >> 7, j = idx & 127;
        sm.w1s[h][j][i] = f2bf(w1p[h][idx]);
      }
      for (int idx = tid; idx < 16*H_; idx += THREADS) {
        int g = idx >> 7, k = idx & 127;
        sm.w2s[h][g][k] = (g < G_) ? f2bf(w2p[h][(size_t)k*G_ + g]) : (short)0;
      }
      if (tid < H_) sm.b1s[h][tid] = b1p[h][tid];
      if (tid < 16) sm.b2s[h][tid] = (tid < G_) ? b2p[h][tid] : 0.0f;
    }
  }

  // ---- convert features to bf16 fragments while staging is in flight ----
  // Used as the MFMA **B** operand: lane holds B[k=(lane>>4)*8+j][col=lane&15=token]
  bf16x8 a1[2][4];
#pragma unroll
  for (int mt = 0; mt < 2; ++mt)
#pragma unroll
    for (int c = 0; c < 4; ++c) {
      float4 lo = fv[mt][c][0], hi = fv[mt][c][1];
      bf16x8 a;
      a[0]=f2bf(lo.x); a[1]=f2bf(lo.y); a[2]=f2bf(lo.z); a[3]=f2bf(lo.w);
      a[4]=f2bf(hi.x); a[5]=f2bf(hi.y); a[6]=f2bf(hi.z); a[7]=f2bf(hi.w);
      a1[mt][c] = a;
    }

  __syncthreads();   // weights visible (compiler drains vmcnt incl. global_load_lds)

  // ---- 3 heads x 2 M-tiles, swapped-operand MFMA: D[j][tok], D[g][tok] ----
  f32x4 lgt[3][2];
#pragma unroll
  for (int h = 0; h < 3; ++h) {
    f32x4 b1v[8];
#pragma unroll
    for (int nt = 0; nt < 8; ++nt)
      b1v[nt] = *reinterpret_cast<const f32x4*>(&sm.b1s[h][nt*16 + q*4]);
    f32x4 b2v = *reinterpret_cast<const f32x4*>(&sm.b2s[h][q*4]);

#pragma unroll
    for (int mt = 0; mt < 2; ++mt) {
      f32x4 acc[8];
#pragma unroll
      for (int nt = 0; nt < 8; ++nt) acc[nt] = (f32x4){0.f,0.f,0.f,0.f};
#pragma unroll
      for (int c = 0; c < 4; ++c) {
#pragma unroll
        for (int nt = 0; nt < 8; ++nt) {
          // A = W1^T tile: lane holds A[row=j=lane&15][k=(lane>>4)*8+j']
          bf16x8 wfr = *reinterpret_cast<const bf16x8*>(&sm.w1s[h][nt*16 + lg][c*32 + q*8]);
          acc[nt] = __builtin_amdgcn_mfma_f32_16x16x32_bf16(wfr, a1[mt][c], acc[nt], 0, 0, 0);
        }
      }
      // D: row = j = q*4+r (4 contiguous j per lane!), col = token = lg
#pragma unroll
      for (int nt = 0; nt < 8; ++nt) {
        bf16x4 pk;
#pragma unroll
        for (int r = 0; r < 4; ++r)
          pk[r] = f2bf(fmaxf(acc[nt][r] + b1v[nt][r], 0.0f));
        *reinterpret_cast<bf16x4*>(&sm.hids[wave][lg][nt*16 + q*4]) = pk;  // one b64 write
      }
      // layer 2: A = W2^T (rows g), B = hidden (cols tok); same-wave DS FIFO, no barrier
      f32x4 lacc = (f32x4){0.f,0.f,0.f,0.f};
#pragma unroll
      for (int c = 0; c < 4; ++c) {
        bf16x8 wfr2 = *reinterpret_cast<const bf16x8*>(&sm.w2s[h][lg][c*32 + q*8]);
        bf16x8 hfr  = *reinterpret_cast<const bf16x8*>(&sm.hids[wave][lg][c*32 + q*8]);
        lacc = __builtin_amdgcn_mfma_f32_16x16x32_bf16(wfr2, hfr, lacc, 0, 0, 0);
      }
      lgt[h][mt] = lacc + b2v;   // D: row = g = q*4+r, col = token = lg
    }
  }

  // ---- epilogue: token = lg; lane holds g = q*4+r; reduce over r (reg) + q (2 shuffles) ----
  float* out_score = out;
  float* out_pi = out + 33;
  float* out_mu = out + 33 + (size_t)TOKS*G_;
  float* out_sg = out + 33 + 2*(size_t)TOKS*G_;
  const float HLOG2PI = 0.91893853320467274f;

  const bool v0 = (q*4+0) < G_, v1 = (q*4+1) < G_, v2 = (q*4+2) < G_, v3 = (q*4+3) < G_;

  float accP = 0.f, accL = 0.f, accC = 0.f;
#pragma unroll
  for (int mt = 0; mt < 2; ++mt) {
    long tok = wtok0 + mt*16 + lg;
    float d  = dpre[mt];
    bool  mk = (mpre[mt] != 0) && (d <= 8.0f);

    f32x4 LP = lgt[0][mt], LS = lgt[1][mt], LM = lgt[2][mt];

    // softmax over g
    float vm = v0 ? LP[0] : -INFINITY;
    if (v1) vm = fmaxf(vm, LP[1]);
    if (v2) vm = fmaxf(vm, LP[2]);
    if (v3) vm = fmaxf(vm, LP[3]);
    vm = fmaxf(vm, __shfl_xor(vm, 16));
    vm = fmaxf(vm, __shfl_xor(vm, 32));
    float e0 = v0 ? __expf(LP[0]-vm) : 0.f;
    float e1 = v1 ? __expf(LP[1]-vm) : 0.f;
    float e2 = v2 ? __expf(LP[2]-vm) : 0.f;
    float e3 = v3 ? __expf(LP[3]-vm) : 0.f;
    float s = e0+e1+e2+e3;
    s += __shfl_xor(s, 16);
    s += __shfl_xor(s, 32);
    float inv = 1.0f / s;
    float pi[4] = {e0*inv, e1*inv, e2*inv, e3*inv};

    float sg[4], mu[4], ll[4];
#pragma unroll
    for (int r = 0; r < 4; ++r) {
      sg[r] = (LS[r] > 0.f) ? (LS[r] + 1.4f) : (__expf(LS[r]) + 0.4f);
      mu[r] = (LM[r] > 0.f) ? (LM[r] + 1.0f) : __expf(LM[r]);
      float z = (d - mu[r]) / sg[r];
      ll[r] = -0.5f*z*z - __logf(sg[r]) - HLOG2PI;
    }

    // stores: 4 contiguous g per lane
    if (q*4 < G_) {
      size_t o = (size_t)tok*G_ + q*4;
      *reinterpret_cast<float2*>(&out_pi[o]) = make_float2(pi[0], pi[1]);
      *reinterpret_cast<float2*>(&out_mu[o]) = make_float2(mu[0], mu[1]);
      *reinterpret_cast<float2*>(&out_sg[o]) = make_float2(sg[0], sg[1]);
      if (q*4+2 < G_) {
        *reinterpret_cast<float2*>(&out_pi[o+2]) = make_float2(pi[2], pi[3]);
        *reinterpret_cast<float2*>(&out_mu[o+2]) = make_float2(mu[2], mu[3]);
        *reinterpret_cast<float2*>(&out_sg[o+2]) = make_float2(sg[2], sg[3]);
      }
    }

    // candidate_loss = -logsumexp(log(pi+eps)+ll)
    float a0 = v0 ? (__logf(pi[0]+1e-10f) + ll[0]) : -INFINITY;
    float a1x= v1 ? (__logf(pi[1]+1e-10f) + ll[1]) : -INFINITY;
    float a2 = v2 ? (__logf(pi[2]+1e-10f) + ll[2]) : -INFINITY;
    float a3 = v3 ? (__logf(pi[3]+1e-10f) + ll[3]) : -INFINITY;
    float m2 = fmaxf(fmaxf(a0,a1x), fmaxf(a2,a3));
    m2 = fmaxf(m2, __shfl_xor(m2, 16));
    m2 = fmaxf(m2, __shfl_xor(m2, 32));
    float s2 = (v0?__expf(a0-m2):0.f) + (v1?__expf(a1x-m2):0.f)
             + (v2?__expf(a2-m2):0.f) + (v3?__expf(a3-m2):0.f);
    s2 += __shfl_xor(s2, 16);
    s2 += __shfl_xor(s2, 32);
    float closs = -(m2 + __logf(s2));

    // prob = sum(exp(ll)*pi)/(d*d+eps)
    float s3 = (v0?__expf(ll[0])*pi[0]:0.f) + (v1?__expf(ll[1])*pi[1]:0.f)
             + (v2?__expf(ll[2])*pi[2]:0.f) + (v3?__expf(ll[3])*pi[3]:0.f);
    s3 += __shfl_xor(s3, 16);
    s3 += __shfl_xor(s3, 32);
    float prob = s3 / (d*d + 1e-10f);

    if (lane < 16 && mk) { accP += prob; accL += closs; accC += 1.f; }
  }

  // reduce over the 16 token-owner lanes (others carry 0)
  accP += __shfl_xor(accP, 1); accP += __shfl_xor(accP, 2);
  accP += __shfl_xor(accP, 4); accP += __shfl_xor(accP, 8);
  accL += __shfl_xor(accL, 1); accL += __shfl_xor(accL, 2);
  accL += __shfl_xor(accL, 4); accL += __shfl_xor(accL, 8);
  accC += __shfl_xor(accC, 1); accC += __shfl_xor(accC, 2);
  accC += __shfl_xor(accC, 4); accC += __shfl_xor(accC, 8);
  if (lane == 0) { sm.red[wave][0] = accP; sm.red[wave][1] = accL; sm.red[wave][2] = accC; }
  __syncthreads();
  if (tid == 0) {
    float sP = 0.f, sL = 0.f, sC = 0.f;
    for (int w = 0; w < WAVES; ++w) { sP += sm.red[w][0]; sL += sm.red[w][1]; sC += sm.red[w][2]; }
    int b = (int)(((long)blockIdx.x * TPB) >> 13);
    atomicAdd(&out_score[b], sP);
    atomicAdd(&ws[0], sL);
    atomicAdd(&ws[1], sC);
  }
}

extern "C" void kernel_launch(void* const* d_in, const int* in_sizes, int n_in,
                              void* d_out, int out_size, void* d_ws, size_t ws_size,
                              hipStream_t stream) {
  const float* feat = (const float*)d_in[0];
  const float* dist = (const float*)d_in[1];
  const int* dmask = (const int*)d_in[2];
  float* out = (float*)d_out;
  float* ws  = (float*)d_ws;

  hipLaunchKernelGGL(init_kernel, dim3(1), dim3(64), 0, stream, out, ws);

  bool prep_ok = (ws_size >= (size_t)(WS_IMG_OFF + IMG_INSTS*1024));
  if (prep_ok) {
    short* img = (short*)((char*)d_ws + WS_IMG_OFF);
    hipLaunchKernelGGL(prep_kernel, dim3(116), dim3(256), 0, stream,
        (const float*)d_in[3],  (const float*)d_in[4],  (const float*)d_in[5],  (const float*)d_in[6],
        (const float*)d_in[7],  (const float*)d_in[8],  (const float*)d_in[9],  (const float*)d_in[10],
        (const float*)d_in[11], (const float*)d_in[12], (const float*)d_in[13], (const float*)d_in[14],
        img);
    hipLaunchKernelGGL((rtm_main<1>), dim3(TOKS/TPB), dim3(THREADS), 0, stream,
        feat, dist, dmask, (const float*)img,
        (const float*)d_in[3],  (const float*)d_in[4],  (const float*)d_in[5],  (const float*)d_in[6],
        (const float*)d_in[7],  (const float*)d_in[8],  (const float*)d_in[9],  (const float*)d_in[10],
        (const float*)d_in[11], (const float*)d_in[12], (const float*)d_in[13], (const float*)d_in[14],
        out, ws);
  } else {
    hipLaunchKernelGGL((rtm_main<0>), dim3(TOKS/TPB), dim3(THREADS), 0, stream,
        feat, dist, dmask, (const float*)nullptr,
        (const float*)d_in[3],  (const float*)d_in[4],  (const float*)d_in[5],  (const float*)d_in[6],
        (const float*)d_in[7],  (const float*)d_in[8],  (const float*)d_in[9],  (const float*)d_in[10],
        (const float*)d_in[11], (const float*)d_in[12], (const float*)d_in[13], (const float*)d_in[14],
        out, ws);
  }

  hipLaunchKernelGGL(fin_kernel, dim3(1), dim3(64), 0, stream, out, ws);
}